// Round 5
// baseline (394.903 us; speedup 1.0000x reference)
//
#include <hip/hip_runtime.h>
#include <math.h>

typedef __bf16 bf16x8 __attribute__((ext_vector_type(8)));
typedef __bf16 bf16x4 __attribute__((ext_vector_type(4)));
typedef short s16x4 __attribute__((ext_vector_type(4)));
typedef float f32x4 __attribute__((ext_vector_type(4)));
typedef unsigned int u32x2 __attribute__((ext_vector_type(2)));
typedef unsigned short u16;
typedef unsigned int u32;

// ---------------- helpers ----------------
__device__ __forceinline__ void gl_lds16(const void* g, void* l) {
  __builtin_amdgcn_global_load_lds(
      (const __attribute__((address_space(1))) void*)g,
      (__attribute__((address_space(3))) void*)l, 16, 0, 0);
}

__device__ __forceinline__ u16 f2bf(float x) {           // RNE f32->bf16
  union { float f; u32 u; } v; v.f = x;
  u32 r = v.u + 0x7FFFu + ((v.u >> 16) & 1u);
  return (u16)(r >> 16);
}

// pack two positive floats to bf16x2 (round-half-up; cheap, bias < 2^-9 rel)
__device__ __forceinline__ u32 pack_bf2(float a, float b) {
  union { float f; u32 u; } ua, ub; ua.f = a; ub.f = b;
  return ((ua.u + 0x8000u) >> 16) | ((ub.u + 0x8000u) & 0xFFFF0000u);
}

// exp2 of pre-scaled input (Q carries 0.125*log2(e)) -> single v_exp_f32
__device__ __forceinline__ float expfast(float x) {
#if __has_builtin(__builtin_amdgcn_exp2f)
  return __builtin_amdgcn_exp2f(x);
#else
  return exp2f(x);
#endif
}

// NOTE (R4 post-mortem): 16x16x16 bf16 MFMA issues in the same ~4.8 cyc as
// 16x16x32 (half throughput). Used only where the operand layout identity
// (S^T C-tile == x16 A-frag) saves a full LDS round-trip, and only while
// the kernel is VALU/latency-bound, not MFMA-bound.
__device__ __forceinline__ f32x4 mfma16(bf16x4 a, bf16x4 b, f32x4 c) {
#if __has_builtin(__builtin_amdgcn_mfma_f32_16x16x16_bf16)
  return __builtin_amdgcn_mfma_f32_16x16x16_bf16(a, b, c, 0, 0, 0);
#else
  return __builtin_amdgcn_mfma_f32_16x16x16bf16_1k(
      __builtin_bit_cast(s16x4, a), __builtin_bit_cast(s16x4, b), c, 0, 0, 0);
#endif
}

__device__ __forceinline__ float gelu_f(float v) {
  return 0.5f * v * (1.0f + erff(v * 0.7071067811865475f));
}

// ---------------- cast fp32 -> bf16, 3 weight matrices in one launch ----------------
__global__ void castbf3(const float* __restrict__ s0, const float* __restrict__ s1,
                        const float* __restrict__ s2, u16* __restrict__ d0,
                        u16* __restrict__ d1, u16* __restrict__ d2) {
  int blk = blockIdx.x;
  const float* s; u16* d;
  if (blk < 768)       { s = s0; d = d0; }
  else if (blk < 1536) { s = s1; d = d1; blk -= 768; }
  else                 { s = s2; d = d2; blk -= 1536; }
  int i = blk * 256 + threadIdx.x;
  float4 v = ((const float4*)s)[i];
  uint2 o;
  o.x = (u32)f2bf(v.x) | ((u32)f2bf(v.y) << 16);
  o.y = (u32)f2bf(v.z) | ((u32)f2bf(v.w) << 16);
  ((uint2*)d)[i] = o;
}

// ---------------- LayerNorm over full [P,E] slab per batch ----------------
__global__ void ln_reduce(const float* __restrict__ src, float2* __restrict__ part) {
  int b = blockIdx.y;
  const float4* p = (const float4*)(src + (size_t)b * 2097152 + (size_t)blockIdx.x * 16384);
  float s = 0.f, q = 0.f;
  #pragma unroll
  for (int i = 0; i < 16; i++) {
    float4 v = p[i * 256 + threadIdx.x];
    s += v.x + v.y + v.z + v.w;
    q += v.x * v.x + v.y * v.y + v.z * v.z + v.w * v.w;
  }
  #pragma unroll
  for (int off = 32; off; off >>= 1) { s += __shfl_down(s, off, 64); q += __shfl_down(q, off, 64); }
  __shared__ float ls[4], lq[4];
  int w = threadIdx.x >> 6;
  if ((threadIdx.x & 63) == 0) { ls[w] = s; lq[w] = q; }
  __syncthreads();
  if (threadIdx.x == 0)
    part[b * 128 + blockIdx.x] =
        make_float2(ls[0] + ls[1] + ls[2] + ls[3], lq[0] + lq[1] + lq[2] + lq[3]);
}

__global__ void ln_final(const float2* __restrict__ part, float2* __restrict__ stats) {
  int b = blockIdx.x, t = threadIdx.x;  // block = 64
  float2 a = part[b * 128 + t], c = part[b * 128 + 64 + t];
  float s = a.x + c.x, q = a.y + c.y;
  #pragma unroll
  for (int off = 32; off; off >>= 1) { s += __shfl_down(s, off, 64); q += __shfl_down(q, off, 64); }
  if (t == 0) {
    const float inv = 1.0f / 2097152.0f;
    float mu = s * inv, var = q * inv - mu * mu;
    stats[b] = make_float2(mu, rsqrtf(var + 1e-5f));
  }
}

__global__ void ln_apply(const float* __restrict__ src, const float* __restrict__ g,
                         const float* __restrict__ bta, const float2* __restrict__ stats,
                         u16* __restrict__ dst) {
  int i = blockIdx.x * 256 + threadIdx.x;  // float4 index, 1048576 total
  int b = i >= 524288;
  float2 st = stats[b];
  int r = i - b * 524288;
  float4 v = ((const float4*)src)[i];
  float4 gv = ((const float4*)g)[r];
  float4 bv = ((const float4*)bta)[r];
  float h0 = (v.x - st.x) * st.y * gv.x + bv.x;
  float h1 = (v.y - st.x) * st.y * gv.y + bv.y;
  float h2 = (v.z - st.x) * st.y * gv.z + bv.z;
  float h3 = (v.w - st.x) * st.y * gv.w + bv.w;
  uint2 o;
  o.x = (u32)f2bf(h0) | ((u32)f2bf(h1) << 16);
  o.y = (u32)f2bf(h2) | ((u32)f2bf(h3) << 16);
  ((uint2*)dst)[i] = o;
}

// ---------------- GEMM: out[m,n] = sum_k A[m,k]*B[n,k]  (B given row-major [N,K]) ----------------
// MODE 0: store bf16; cols<512 (Q) pre-scaled by 0.125*log2(e) so softmax exp is exp2.
// MODE 1: gelu(x+bias) -> bf16.  MODE 2: gelu(x+bias)+res -> fp32.
template <int MODE>
__global__ __launch_bounds__(256, 2)
void gemm_bt(const u16* __restrict__ A, const u16* __restrict__ Bm,
             const float* __restrict__ bias, const float* __restrict__ res,
             float* __restrict__ outf, u16* __restrict__ outb,
             int M, int N, int K) {
  __shared__ u16 As[128 * 32], Bs[128 * 32];
  const int tid = threadIdx.x;
  const int m0 = blockIdx.y * 128, n0 = blockIdx.x * 128;
  const int lane = tid & 63, w = tid >> 6;
  const int wm = (w >> 1) * 64, wn = (w & 1) * 64;
  const int c = lane & 15, quad = lane >> 4;
  const int arow = tid >> 2, acol = (tid & 3) * 8;

  const u16* gA = A + (size_t)(m0 + arow) * K + acol;
  const u16* gB = Bm + (size_t)(n0 + arow) * K + acol;
  u16* lA = As + tid * 8;
  u16* lB = Bs + tid * 8;

  f32x4 acc[4][4] = {};
  for (int kt = 0; kt < K; kt += 32) {
    gl_lds16(gA, lA);
    gl_lds16(gA + (size_t)64 * K, lA + 64 * 32);
    gl_lds16(gB, lB);
    gl_lds16(gB + (size_t)64 * K, lB + 64 * 32);
    gA += 32; gB += 32;
    __syncthreads();
    bf16x8 af[4], bf[4];
    #pragma unroll
    for (int i = 0; i < 4; i++) {
      af[i] = *(const bf16x8*)&As[(wm + i * 16 + c) * 32 + quad * 8];
      bf[i] = *(const bf16x8*)&Bs[(wn + i * 16 + c) * 32 + quad * 8];
    }
    #pragma unroll
    for (int i = 0; i < 4; i++)
      #pragma unroll
      for (int j = 0; j < 4; j++)
        acc[i][j] = __builtin_amdgcn_mfma_f32_16x16x32_bf16(af[i], bf[j], acc[i][j], 0, 0, 0);
    __syncthreads();
  }
  #pragma unroll
  for (int i = 0; i < 4; i++) {
    const int row0 = m0 + wm + i * 16 + quad * 4;
    #pragma unroll
    for (int j = 0; j < 4; j++) {
      const int col = n0 + wn + j * 16 + c;
      #pragma unroll
      for (int r = 0; r < 4; r++) {
        float v = acc[i][j][r];
        size_t oi = (size_t)(row0 + r) * N + col;
        if (MODE == 0 && col < 512) v *= 0.1803368801111204f;  // 1/8 * log2(e)
        if (MODE == 1 || MODE == 2) v = gelu_f(v + bias[col]);
        if (MODE == 2) outf[oi] = v + res[oi];
        else           outb[oi] = f2bf(v);
      }
    }
  }
}

// ---------------- attention pass 1: partial column sums of exp2(K Q^T) ----------------
__global__ __launch_bounds__(256, 4)
void attn_pass1(const u16* __restrict__ qkv, float* __restrict__ rlpart) {
  __shared__ u16 Qs[2][2 * 128 * 32];   // 2 buf x (2 panels x 128x32) = 32 KB
  const int tid = threadIdx.x;
  const int bh = blockIdx.y, b = bh >> 3, h = bh & 7;
  const int k0 = blockIdx.x * 128;
  const int lane = tid & 63, w = tid >> 6;
  const int wn = w * 32;                 // each warp owns 32 k-columns
  const int c = lane & 15, quad = lane >> 4;
  const int arow = tid >> 2, acol = (tid & 3) * 8;

  bf16x8 bk[2][2];
  {
    const u16* Kg = qkv + ((size_t)(b * 4096 + k0 + wn + c)) * 1536 + 512 + h * 64 + quad * 8;
    #pragma unroll
    for (int j = 0; j < 2; j++)
      #pragma unroll
      for (int ks = 0; ks < 2; ks++)
        bk[j][ks] = *(const bf16x8*)(Kg + (size_t)j * 16 * 1536 + ks * 32);
  }
  const u16* Qg = qkv + ((size_t)(b * 4096 + blockIdx.z * 2048)) * 1536 + h * 64;

  #define STAGE_Q(t)                                                              \
    {                                                                             \
      u16* dst = Qs[(t) & 1];                                                     \
      const u16* src = Qg + (size_t)((t) * 128) * 1536;                           \
      _Pragma("unroll")                                                           \
      for (int ks = 0; ks < 2; ks++)                                              \
        _Pragma("unroll")                                                         \
        for (int rr = 0; rr < 128; rr += 64)                                      \
          gl_lds16(src + (size_t)(rr + arow) * 1536 + ks * 32 + acol,             \
                   dst + ks * 4096 + (rr + arow) * 32 + acol);                    \
    }

  STAGE_Q(0);
  float s0 = 0.f, s1 = 0.f;
  for (int t = 0; t < 16; t++) {
    __syncthreads();
    if (t + 1 < 16) STAGE_Q(t + 1);
    const u16* buf = Qs[t & 1];
    #pragma unroll
    for (int i = 0; i < 8; i++) {
      bf16x8 a0 = *(const bf16x8*)&buf[(i * 16 + c) * 32 + quad * 8];
      bf16x8 a1 = *(const bf16x8*)&buf[4096 + (i * 16 + c) * 32 + quad * 8];
      f32x4 acc0 = {}, acc1 = {};
      acc0 = __builtin_amdgcn_mfma_f32_16x16x32_bf16(a0, bk[0][0], acc0, 0, 0, 0);
      acc0 = __builtin_amdgcn_mfma_f32_16x16x32_bf16(a1, bk[0][1], acc0, 0, 0, 0);
      acc1 = __builtin_amdgcn_mfma_f32_16x16x32_bf16(a0, bk[1][0], acc1, 0, 0, 0);
      acc1 = __builtin_amdgcn_mfma_f32_16x16x32_bf16(a1, bk[1][1], acc1, 0, 0, 0);
      #pragma unroll
      for (int r = 0; r < 4; r++) {
        s0 += expfast(acc0[r]);
        s1 += expfast(acc1[r]);
      }
    }
  }
  #undef STAGE_Q
  s0 += __shfl_xor(s0, 16, 64); s0 += __shfl_xor(s0, 32, 64);
  s1 += __shfl_xor(s1, 16, 64); s1 += __shfl_xor(s1, 32, 64);
  if (quad == 0) {
    float* rp = rlpart + ((size_t)blockIdx.z * 16 + bh) * 4096 + k0 + wn;
    rp[c] = s0;
    rp[16 + c] = s1;
  }
}

// combine the two q-half partials: rl = 1/(p0+p1)
__global__ void rl_comb(const float* __restrict__ part, float* __restrict__ rl) {
  int i = blockIdx.x * 256 + threadIdx.x;  // 65536 total
  rl[i] = 1.0f / (part[i] + part[65536 + i]);
}

// ---------------- transpose+scale V into swizzled k-tiled layout ----------------
// vt_sw[bh][kt(64)][d(64)][blk(8) ^ (d&7)][8 u16] = V[p=kt*64+...][d] * rl[bh][p]
__global__ void vtrans(const u16* __restrict__ qkv, const float* __restrict__ rl,
                       u16* __restrict__ vt) {
  __shared__ u16 t[64 * 66];
  int bh = blockIdx.y, p0 = blockIdx.x * 64;
  int b = bh >> 3, h = bh & 7;
  const u16* src = qkv + ((size_t)(b * 4096 + p0)) * 1536 + 1024 + h * 64;
  const float* rp = rl + (size_t)bh * 4096 + p0;
  int tid = threadIdx.x;
  #pragma unroll
  for (int j = 0; j < 16; j++) {
    int idx = j * 256 + tid;
    int p = idx >> 6, d = idx & 63;
    union { float f; u32 u; } uv;
    uv.u = ((u32)src[(size_t)p * 1536 + d]) << 16;
    t[d * 66 + p] = f2bf(uv.f * rp[p]);
  }
  __syncthreads();
  u16* dst = vt + (size_t)bh * 262144 + (size_t)blockIdx.x * 4096;
  #pragma unroll
  for (int j = 0; j < 16; j++) {
    int idx = j * 256 + tid;
    int d = idx >> 6, p = idx & 63;
    dst[d * 64 + ((((p >> 3) & 7) ^ (d & 7)) << 3) + (p & 7)] = t[d * 66 + p];
  }
}

// ---------------- attention pass 2: out1 = x + P@V' (V' pre-scaled by rl) ----------------
// 16 q per warp / 64 q per block -> 1024 blocks = 4 blocks/CU, 16 waves/CU
// (R4's 512-block grid capped occupancy at 2 waves/SIMD; latency-bound).
// S^T = K Q^T via x32 (K rows as A); C-tile == x16 A-frag, so exp+pack feed PV
// from registers. K/V double-buffered, 1 barrier/t.
__global__ __launch_bounds__(256, 4)
void attn_pass2(const u16* __restrict__ qkv, const u16* __restrict__ vt,
                const float* __restrict__ x, float* __restrict__ out1) {
  __shared__ u16 Ks[2][2][2048];  // [buf][dk-panel][64k x 32] = 16 KB
  __shared__ u16 Vs[2][4096];     // [buf][64d x 64k swizzled] = 16 KB
  const int tid = threadIdx.x;
  const int bh = blockIdx.y, b = bh >> 3, h = bh & 7;
  const int q0 = blockIdx.x * 64;
  const int lane = tid & 63, w = tid >> 6;
  const int wq = w * 16;                 // each warp owns 16 q-rows
  const int c = lane & 15, quad = lane >> 4;

  // resident Q fragments (B-operand): q = q0+wq+c, dk = ks*32+quad*8
  bf16x8 bq[2];
  {
    const u16* Qg = qkv + ((size_t)(b * 4096 + q0 + wq + c)) * 1536 + h * 64 + quad * 8;
    #pragma unroll
    for (int ks = 0; ks < 2; ks++)
      bq[ks] = *(const bf16x8*)(Qg + ks * 32);
  }
  const u16* Kg = qkv + ((size_t)b * 4096) * 1536 + 512 + h * 64;
  const u16* Vg = vt + (size_t)bh * 262144;

  #define STAGE_KV(t)                                                             \
    {                                                                             \
      const int buf_ = (t) & 1;                                                   \
      const int krow_ = (t) * 64 + (tid >> 2);                                    \
      _Pragma("unroll")                                                           \
      for (int ks = 0; ks < 2; ks++)                                              \
        gl_lds16(Kg + (size_t)krow_ * 1536 + ks * 32 + (tid & 3) * 8,             \
                 &Ks[buf_][ks][tid * 8]);                                         \
      gl_lds16(Vg + (t) * 4096 + tid * 8, &Vs[buf_][tid * 8]);                    \
      gl_lds16(Vg + (t) * 4096 + 2048 + tid * 8, &Vs[buf_][2048 + tid * 8]);      \
    }

  STAGE_KV(0);
  f32x4 oacc[4] = {};
  for (int t = 0; t < 64; t++) {
    __syncthreads();                     // buf t ready (vmcnt drained at barrier)
    if (t + 1 < 64) STAGE_KV(t + 1);     // prefetch overlaps compute below
    const int buf = t & 1;

    // ---- S^T = K Q^T (4 k-tiles x 1 q-tile)
    f32x4 sacc[4] = {};
    #pragma unroll
    for (int i = 0; i < 4; i++) {
      bf16x8 af0 = *(const bf16x8*)&Ks[buf][0][(i * 16 + c) * 32 + quad * 8];
      bf16x8 af1 = *(const bf16x8*)&Ks[buf][1][(i * 16 + c) * 32 + quad * 8];
      sacc[i] = __builtin_amdgcn_mfma_f32_16x16x32_bf16(af0, bq[0], sacc[i], 0, 0, 0);
      sacc[i] = __builtin_amdgcn_mfma_f32_16x16x32_bf16(af1, bq[1], sacc[i], 0, 0, 0);
    }
    // ---- P = exp2(S^T), packed in-register into 16x16x16 A-fragments
    bf16x4 pa[4];
    #pragma unroll
    for (int i = 0; i < 4; i++) {
      u32x2 pk;
      pk.x = pack_bf2(expfast(sacc[i][0]), expfast(sacc[i][1]));
      pk.y = pack_bf2(expfast(sacc[i][2]), expfast(sacc[i][3]));
      pa[i] = __builtin_bit_cast(bf16x4, pk);
    }
    // ---- O += P V' (16x16x16; V B-frags b64 from swizzled Vs)
    #pragma unroll
    for (int kc = 0; kc < 4; kc++) {
      const int kb = 2 * kc + (quad >> 1);
      #pragma unroll
      for (int j2 = 0; j2 < 4; j2++) {
        const int d = j2 * 16 + c;
        bf16x4 vf = *(const bf16x4*)&Vs[buf][d * 64 + ((kb ^ (d & 7)) << 3) + 4 * (quad & 1)];
        oacc[j2] = mfma16(pa[kc], vf, oacc[j2]);
      }
    }
  }
  #undef STAGE_KV
  // ---- epilogue: out1 = x + O
  #pragma unroll
  for (int j2 = 0; j2 < 4; j2++)
    #pragma unroll
    for (int r = 0; r < 4; r++) {
      const int q = q0 + wq + quad * 4 + r;
      const int d = j2 * 16 + c;
      size_t oi = ((size_t)(b * 4096 + q)) * 512 + h * 64 + d;
      out1[oi] = x[oi] + oacc[j2][r];
    }
}

// ---------------- launch ----------------
extern "C" void kernel_launch(void* const* d_in, const int* in_sizes, int n_in,
                              void* d_out, int out_size, void* d_ws, size_t ws_size,
                              hipStream_t stream) {
  const float* x  = (const float*)d_in[0];
  const float* g1 = (const float*)d_in[1];
  const float* b1 = (const float*)d_in[2];
  const float* W1 = (const float*)d_in[3];
  const float* g2 = (const float*)d_in[4];
  const float* b2 = (const float*)d_in[5];
  const float* Wa = (const float*)d_in[6];
  const float* ba = (const float*)d_in[7];
  const float* Wb = (const float*)d_in[8];
  const float* bb = (const float*)d_in[9];
  float* out = (float*)d_out;

  char* ws = (char*)d_ws;
  u16* w1b   = (u16*)(ws);                       // 1.5 MB
  u16* wab   = (u16*)(ws + 1572864);             // 1.5 MB
  u16* wbb   = (u16*)(ws + 3145728);             // 1.5 MB
  u16* h1    = (u16*)(ws + 4718592);             // 8 MB
  u16* qkv   = (u16*)(ws + 13107200);            // 24 MB
  u16* vt    = (u16*)(ws + 38273024);            // 8 MB
  u16* h2    = (u16*)(ws + 46661632);            // 8 MB
  u16* mid   = (u16*)(ws + 55050240);            // 24 MB (also rlpart before gemm1)
  float* rl  = (float*)(ws + 80216064);          // 256 KB
  float* o1  = (float*)(ws + 80478208);          // 16 MB
  float2* part  = (float2*)(ws + 97255424);      // 2 KB
  float2* stats = (float2*)(ws + 97257472);      // 16 B
  float* rlpart = (float*)(ws + 55050240);       // 512 KB, aliases mid (free until gemm1)

  castbf3<<<2304, 256, 0, stream>>>(W1, Wa, Wb, w1b, wab, wbb);

  ln_reduce<<<dim3(128, 2), 256, 0, stream>>>(x, part);
  ln_final<<<2, 64, 0, stream>>>(part, stats);
  ln_apply<<<4096, 256, 0, stream>>>(x, g1, b1, stats, h1);

  gemm_bt<0><<<dim3(12, 64), 256, 0, stream>>>(h1, w1b, nullptr, nullptr, nullptr, qkv,
                                               8192, 1536, 512);
  attn_pass1<<<dim3(32, 16, 2), 256, 0, stream>>>(qkv, rlpart);
  rl_comb<<<256, 256, 0, stream>>>(rlpart, rl);
  vtrans<<<dim3(64, 16), 256, 0, stream>>>(qkv, rl, vt);
  attn_pass2<<<dim3(64, 16), 256, 0, stream>>>(qkv, vt, x, o1);

  ln_reduce<<<dim3(128, 2), 256, 0, stream>>>(o1, part);
  ln_final<<<2, 64, 0, stream>>>(part, stats);
  ln_apply<<<4096, 256, 0, stream>>>(o1, g2, b2, stats, h2);

  gemm_bt<1><<<dim3(12, 64), 256, 0, stream>>>(h2, wab, ba, nullptr, nullptr, mid,
                                               8192, 1536, 512);
  gemm_bt<2><<<dim3(4, 64), 256, 0, stream>>>(mid, wbb, bb, o1, out, nullptr,
                                              8192, 512, 1536);
}

// Round 6
// 367.348 us; speedup vs baseline: 1.0750x; 1.0750x over previous
//
#include <hip/hip_runtime.h>
#include <math.h>

typedef __bf16 bf16x8 __attribute__((ext_vector_type(8)));
typedef __bf16 bf16x4 __attribute__((ext_vector_type(4)));
typedef float f32x4 __attribute__((ext_vector_type(4)));
typedef unsigned short u16;
typedef unsigned int u32;

// ---------------- helpers ----------------
__device__ __forceinline__ void gl_lds16(const void* g, void* l) {
  __builtin_amdgcn_global_load_lds(
      (const __attribute__((address_space(1))) void*)g,
      (__attribute__((address_space(3))) void*)l, 16, 0, 0);
}

__device__ __forceinline__ u16 f2bf(float x) {           // RNE f32->bf16
  union { float f; u32 u; } v; v.f = x;
  u32 r = v.u + 0x7FFFu + ((v.u >> 16) & 1u);
  return (u16)(r >> 16);
}

// pack two positive floats to bf16x2 (round-half-up; cheap, bias < 2^-9 rel)
__device__ __forceinline__ u32 pack_bf2(float a, float b) {
  union { float f; u32 u; } ua, ub; ua.f = a; ub.f = b;
  return ((ua.u + 0x8000u) >> 16) | ((ub.u + 0x8000u) & 0xFFFF0000u);
}

// exp2 of pre-scaled input (Q carries 0.125*log2(e)) -> single v_exp_f32
__device__ __forceinline__ float expfast(float x) {
#if __has_builtin(__builtin_amdgcn_exp2f)
  return __builtin_amdgcn_exp2f(x);
#else
  return exp2f(x);
#endif
}

__device__ __forceinline__ float gelu_f(float v) {
  return 0.5f * v * (1.0f + erff(v * 0.7071067811865475f));
}

// ---------------- fused: cast 3 weight matrices + ln_reduce(x) ----------------
// blocks 0..2303: bf16 casts; blocks 2304..2559: ln partial sums for x.
__global__ void cast_lnred(const float* __restrict__ s0, const float* __restrict__ s1,
                           const float* __restrict__ s2, u16* __restrict__ d0,
                           u16* __restrict__ d1, u16* __restrict__ d2,
                           const float* __restrict__ x, float2* __restrict__ part) {
  int blk = blockIdx.x;
  if (blk < 2304) {
    const float* s; u16* d;
    if (blk < 768)       { s = s0; d = d0; }
    else if (blk < 1536) { s = s1; d = d1; blk -= 768; }
    else                 { s = s2; d = d2; blk -= 1536; }
    int i = blk * 256 + threadIdx.x;
    float4 v = ((const float4*)s)[i];
    uint2 o;
    o.x = (u32)f2bf(v.x) | ((u32)f2bf(v.y) << 16);
    o.y = (u32)f2bf(v.z) | ((u32)f2bf(v.w) << 16);
    ((uint2*)d)[i] = o;
    return;
  }
  blk -= 2304;                       // 256 reduce blocks: [b(2)][i(128)]
  int b = blk >> 7, ib = blk & 127;
  const float4* p = (const float4*)(x + (size_t)b * 2097152 + (size_t)ib * 16384);
  float s = 0.f, q = 0.f;
  #pragma unroll
  for (int i = 0; i < 16; i++) {
    float4 v = p[i * 256 + threadIdx.x];
    s += v.x + v.y + v.z + v.w;
    q += v.x * v.x + v.y * v.y + v.z * v.z + v.w * v.w;
  }
  #pragma unroll
  for (int off = 32; off; off >>= 1) { s += __shfl_down(s, off, 64); q += __shfl_down(q, off, 64); }
  __shared__ float ls[4], lq[4];
  int w = threadIdx.x >> 6;
  if ((threadIdx.x & 63) == 0) { ls[w] = s; lq[w] = q; }
  __syncthreads();
  if (threadIdx.x == 0)
    part[b * 128 + ib] =
        make_float2(ls[0] + ls[1] + ls[2] + ls[3], lq[0] + lq[1] + lq[2] + lq[3]);
}

// ---------------- standalone ln_reduce (for o1) ----------------
__global__ void ln_reduce(const float* __restrict__ src, float2* __restrict__ part) {
  int b = blockIdx.y;
  const float4* p = (const float4*)(src + (size_t)b * 2097152 + (size_t)blockIdx.x * 16384);
  float s = 0.f, q = 0.f;
  #pragma unroll
  for (int i = 0; i < 16; i++) {
    float4 v = p[i * 256 + threadIdx.x];
    s += v.x + v.y + v.z + v.w;
    q += v.x * v.x + v.y * v.y + v.z * v.z + v.w * v.w;
  }
  #pragma unroll
  for (int off = 32; off; off >>= 1) { s += __shfl_down(s, off, 64); q += __shfl_down(q, off, 64); }
  __shared__ float ls[4], lq[4];
  int w = threadIdx.x >> 6;
  if ((threadIdx.x & 63) == 0) { ls[w] = s; lq[w] = q; }
  __syncthreads();
  if (threadIdx.x == 0)
    part[b * 128 + blockIdx.x] =
        make_float2(ls[0] + ls[1] + ls[2] + ls[3], lq[0] + lq[1] + lq[2] + lq[3]);
}

// ---------------- ln_apply with inline final reduction (128 partials/batch) ----------------
__global__ void ln_apply(const float* __restrict__ src, const float* __restrict__ g,
                         const float* __restrict__ bta, const float2* __restrict__ part,
                         u16* __restrict__ dst) {
  int i = blockIdx.x * 256 + threadIdx.x;  // float4 index, 1048576 total
  int b = i >= 524288;
  int lane = threadIdx.x & 63;
  float2 a = part[b * 128 + lane], c2 = part[b * 128 + 64 + lane];
  float s = a.x + c2.x, q = a.y + c2.y;
  #pragma unroll
  for (int off = 32; off; off >>= 1) { s += __shfl_down(s, off, 64); q += __shfl_down(q, off, 64); }
  s = __shfl(s, 0, 64); q = __shfl(q, 0, 64);
  const float inv = 1.0f / 2097152.0f;
  float mu = s * inv;
  float rsig = rsqrtf(q * inv - mu * mu + 1e-5f);
  int r = i - b * 524288;
  float4 v = ((const float4*)src)[i];
  float4 gv = ((const float4*)g)[r];
  float4 bv = ((const float4*)bta)[r];
  float h0 = (v.x - mu) * rsig * gv.x + bv.x;
  float h1 = (v.y - mu) * rsig * gv.y + bv.y;
  float h2 = (v.z - mu) * rsig * gv.z + bv.z;
  float h3 = (v.w - mu) * rsig * gv.w + bv.w;
  uint2 o;
  o.x = (u32)f2bf(h0) | ((u32)f2bf(h1) << 16);
  o.y = (u32)f2bf(h2) | ((u32)f2bf(h3) << 16);
  ((uint2*)dst)[i] = o;
}

// ---------------- GEMM: out[m,n] = sum_k A[m,k]*B[n,k]  (B given row-major [N,K]) ----------------
// MODE 0: store bf16; cols<512 (Q) pre-scaled by 0.125*log2(e) so softmax exp is exp2.
// MODE 1: gelu(x+bias) -> bf16.  MODE 2: gelu(x+bias)+res -> fp32.
template <int MODE>
__global__ __launch_bounds__(256, 2)
void gemm_bt(const u16* __restrict__ A, const u16* __restrict__ Bm,
             const float* __restrict__ bias, const float* __restrict__ res,
             float* __restrict__ outf, u16* __restrict__ outb,
             int M, int N, int K) {
  __shared__ u16 As[128 * 32], Bs[128 * 32];
  const int tid = threadIdx.x;
  const int m0 = blockIdx.y * 128, n0 = blockIdx.x * 128;
  const int lane = tid & 63, w = tid >> 6;
  const int wm = (w >> 1) * 64, wn = (w & 1) * 64;
  const int c = lane & 15, quad = lane >> 4;
  const int arow = tid >> 2, acol = (tid & 3) * 8;

  const u16* gA = A + (size_t)(m0 + arow) * K + acol;
  const u16* gB = Bm + (size_t)(n0 + arow) * K + acol;
  u16* lA = As + tid * 8;
  u16* lB = Bs + tid * 8;

  f32x4 acc[4][4] = {};
  for (int kt = 0; kt < K; kt += 32) {
    gl_lds16(gA, lA);
    gl_lds16(gA + (size_t)64 * K, lA + 64 * 32);
    gl_lds16(gB, lB);
    gl_lds16(gB + (size_t)64 * K, lB + 64 * 32);
    gA += 32; gB += 32;
    __syncthreads();
    bf16x8 af[4], bf[4];
    #pragma unroll
    for (int i = 0; i < 4; i++) {
      af[i] = *(const bf16x8*)&As[(wm + i * 16 + c) * 32 + quad * 8];
      bf[i] = *(const bf16x8*)&Bs[(wn + i * 16 + c) * 32 + quad * 8];
    }
    #pragma unroll
    for (int i = 0; i < 4; i++)
      #pragma unroll
      for (int j = 0; j < 4; j++)
        acc[i][j] = __builtin_amdgcn_mfma_f32_16x16x32_bf16(af[i], bf[j], acc[i][j], 0, 0, 0);
    __syncthreads();
  }
  #pragma unroll
  for (int i = 0; i < 4; i++) {
    const int row0 = m0 + wm + i * 16 + quad * 4;
    #pragma unroll
    for (int j = 0; j < 4; j++) {
      const int col = n0 + wn + j * 16 + c;
      #pragma unroll
      for (int r = 0; r < 4; r++) {
        float v = acc[i][j][r];
        size_t oi = (size_t)(row0 + r) * N + col;
        if (MODE == 0 && col < 512) v *= 0.1803368801111204f;  // 1/8 * log2(e)
        if (MODE == 1 || MODE == 2) v = gelu_f(v + bias[col]);
        if (MODE == 2) outf[oi] = v + res[oi];
        else           outb[oi] = f2bf(v);
      }
    }
  }
}

// ---------------- attention pass 1: partial column sums of exp2(K Q^T) ----------------
__global__ __launch_bounds__(256, 4)
void attn_pass1(const u16* __restrict__ qkv, float* __restrict__ rlpart) {
  __shared__ u16 Qs[2][2 * 128 * 32];   // 2 buf x (2 panels x 128x32) = 32 KB
  const int tid = threadIdx.x;
  const int bh = blockIdx.y, b = bh >> 3, h = bh & 7;
  const int k0 = blockIdx.x * 128;
  const int lane = tid & 63, w = tid >> 6;
  const int wn = w * 32;                 // each warp owns 32 k-columns
  const int c = lane & 15, quad = lane >> 4;
  const int arow = tid >> 2, acol = (tid & 3) * 8;

  bf16x8 bk[2][2];
  {
    const u16* Kg = qkv + ((size_t)(b * 4096 + k0 + wn + c)) * 1536 + 512 + h * 64 + quad * 8;
    #pragma unroll
    for (int j = 0; j < 2; j++)
      #pragma unroll
      for (int ks = 0; ks < 2; ks++)
        bk[j][ks] = *(const bf16x8*)(Kg + (size_t)j * 16 * 1536 + ks * 32);
  }
  const u16* Qg = qkv + ((size_t)(b * 4096 + blockIdx.z * 2048)) * 1536 + h * 64;

  #define STAGE_Q(t)                                                              \
    {                                                                             \
      u16* dst = Qs[(t) & 1];                                                     \
      const u16* src = Qg + (size_t)((t) * 128) * 1536;                           \
      _Pragma("unroll")                                                           \
      for (int ks = 0; ks < 2; ks++)                                              \
        _Pragma("unroll")                                                         \
        for (int rr = 0; rr < 128; rr += 64)                                      \
          gl_lds16(src + (size_t)(rr + arow) * 1536 + ks * 32 + acol,             \
                   dst + ks * 4096 + (rr + arow) * 32 + acol);                    \
    }

  STAGE_Q(0);
  float s0 = 0.f, s1 = 0.f;
  for (int t = 0; t < 16; t++) {
    __syncthreads();
    if (t + 1 < 16) STAGE_Q(t + 1);
    const u16* buf = Qs[t & 1];
    #pragma unroll
    for (int i = 0; i < 8; i++) {
      bf16x8 a0 = *(const bf16x8*)&buf[(i * 16 + c) * 32 + quad * 8];
      bf16x8 a1 = *(const bf16x8*)&buf[4096 + (i * 16 + c) * 32 + quad * 8];
      f32x4 acc0 = {}, acc1 = {};
      acc0 = __builtin_amdgcn_mfma_f32_16x16x32_bf16(a0, bk[0][0], acc0, 0, 0, 0);
      acc0 = __builtin_amdgcn_mfma_f32_16x16x32_bf16(a1, bk[0][1], acc0, 0, 0, 0);
      acc1 = __builtin_amdgcn_mfma_f32_16x16x32_bf16(a0, bk[1][0], acc1, 0, 0, 0);
      acc1 = __builtin_amdgcn_mfma_f32_16x16x32_bf16(a1, bk[1][1], acc1, 0, 0, 0);
      #pragma unroll
      for (int r = 0; r < 4; r++) {
        s0 += expfast(acc0[r]);
        s1 += expfast(acc1[r]);
      }
    }
  }
  #undef STAGE_Q
  s0 += __shfl_xor(s0, 16, 64); s0 += __shfl_xor(s0, 32, 64);
  s1 += __shfl_xor(s1, 16, 64); s1 += __shfl_xor(s1, 32, 64);
  if (quad == 0) {
    float* rp = rlpart + ((size_t)blockIdx.z * 16 + bh) * 4096 + k0 + wn;
    rp[c] = s0;
    rp[16 + c] = s1;
  }
}

// ---------------- transpose+scale V (inline rl = 1/(part0+part1)) ----------------
// vt[bh][kt(64)][d(64)][(blk ^ (d&7)) * 8 + (k&7)] = V[k][d] * rl[bh][k]
__global__ void vtrans(const u16* __restrict__ qkv, const float* __restrict__ rlpart,
                       u16* __restrict__ vt) {
  __shared__ u16 t[64 * 66];
  __shared__ float rls[64];
  int bh = blockIdx.y, p0 = blockIdx.x * 64;
  int b = bh >> 3, h = bh & 7;
  const u16* src = qkv + ((size_t)(b * 4096 + p0)) * 1536 + 1024 + h * 64;
  int tid = threadIdx.x;
  if (tid < 64) {
    size_t idx = (size_t)bh * 4096 + p0 + tid;
    rls[tid] = 1.0f / (rlpart[idx] + rlpart[65536 + idx]);
  }
  __syncthreads();
  #pragma unroll
  for (int j = 0; j < 16; j++) {
    int idx = j * 256 + tid;
    int p = idx >> 6, d = idx & 63;
    union { float f; u32 u; } uv;
    uv.u = ((u32)src[(size_t)p * 1536 + d]) << 16;
    t[d * 66 + p] = f2bf(uv.f * rls[p]);
  }
  __syncthreads();
  u16* dst = vt + (size_t)bh * 262144 + (size_t)blockIdx.x * 4096;
  #pragma unroll
  for (int j = 0; j < 16; j++) {
    int idx = j * 256 + tid;
    int d = idx >> 6, p = idx & 63;
    dst[d * 64 + ((((p >> 3) & 7) ^ (d & 7)) << 3) + (p & 7)] = t[d * 66 + p];
  }
}

// ---------------- attention pass 2: out1 = x + P@V' (V' pre-scaled by rl) ----------------
// 128q block, 32q/warp (LDS-traffic sweet spot), 64k chunks, K/V double-buffered ->
// 1 barrier/t. S^T = K Q^T (x32). P round-trips through LDS with 16B-block XOR
// swizzle (write b64, read b128, both bank-minimal), same-warp so no barrier.
// PV = x32 (full-rate MFMA). V read b128 from XOR-swizzled Vs.
__global__ __launch_bounds__(256, 2)
void attn_pass2(const u16* __restrict__ qkv, const u16* __restrict__ vt,
                const float* __restrict__ x, float* __restrict__ out1) {
  __shared__ u16 Ks[2][2][2048];   // [buf][dk-panel][64k x 32] = 16 KB
  __shared__ u16 Vs[2][4096];      // [buf][64d x 64k swizzled] = 16 KB
  __shared__ u16 Ps[128][64];      // [q][64k swizzled] = 16 KB
  const int tid = threadIdx.x;
  const int bh = blockIdx.y, b = bh >> 3, h = bh & 7;
  const int q0 = blockIdx.x * 128;
  const int lane = tid & 63, w = tid >> 6;
  const int wq = w * 32;                 // each warp owns 32 q-rows
  const int c = lane & 15, quad = lane >> 4;

  // resident Q fragments (B-operand): q = q0+wq+j*16+c, dk = ks*32+quad*8
  bf16x8 bq[2][2];
  {
    const u16* Qg = qkv + ((size_t)(b * 4096 + q0 + wq + c)) * 1536 + h * 64 + quad * 8;
    #pragma unroll
    for (int j = 0; j < 2; j++)
      #pragma unroll
      for (int ks = 0; ks < 2; ks++)
        bq[j][ks] = *(const bf16x8*)(Qg + (size_t)j * 16 * 1536 + ks * 32);
  }
  const u16* Kg = qkv + ((size_t)b * 4096) * 1536 + 512 + h * 64;
  const u16* Vg = vt + (size_t)bh * 262144;

  #define STAGE_KV(t)                                                             \
    {                                                                             \
      const int buf_ = (t) & 1;                                                   \
      const int krow_ = (t) * 64 + (tid >> 2);                                    \
      _Pragma("unroll")                                                           \
      for (int ks = 0; ks < 2; ks++)                                              \
        gl_lds16(Kg + (size_t)krow_ * 1536 + ks * 32 + (tid & 3) * 8,             \
                 &Ks[buf_][ks][tid * 8]);                                         \
      gl_lds16(Vg + (t) * 4096 + tid * 8, &Vs[buf_][tid * 8]);                    \
      gl_lds16(Vg + (t) * 4096 + 2048 + tid * 8, &Vs[buf_][2048 + tid * 8]);      \
    }

  STAGE_KV(0);
  f32x4 oacc[2][4] = {};
  for (int t = 0; t < 64; t++) {
    __syncthreads();                     // buf t ready (vmcnt drained at barrier)
    if (t + 1 < 64) STAGE_KV(t + 1);     // prefetch overlaps compute below
    const int buf = t & 1;

    // ---- S^T = K Q^T (4 k-tiles x 2 q-tiles)
    f32x4 sacc[4][2] = {};
    #pragma unroll
    for (int i = 0; i < 4; i++) {
      bf16x8 af0 = *(const bf16x8*)&Ks[buf][0][(i * 16 + c) * 32 + quad * 8];
      bf16x8 af1 = *(const bf16x8*)&Ks[buf][1][(i * 16 + c) * 32 + quad * 8];
      #pragma unroll
      for (int j = 0; j < 2; j++) {
        sacc[i][j] = __builtin_amdgcn_mfma_f32_16x16x32_bf16(af0, bq[j][0], sacc[i][j], 0, 0, 0);
        sacc[i][j] = __builtin_amdgcn_mfma_f32_16x16x32_bf16(af1, bq[j][1], sacc[i][j], 0, 0, 0);
      }
    }
    // ---- P = exp2(S^T) -> LDS [q][k], b64 writes into swizzled 16B half-blocks
    // lane holds k_local = i*16 + quad*4 + r at q = wq + j*16 + c
    #pragma unroll
    for (int i = 0; i < 4; i++) {
      const int blk = i * 2 + (quad >> 1);
      #pragma unroll
      for (int j = 0; j < 2; j++) {
        const int qloc = wq + j * 16 + c;
        u16* pp = &Ps[qloc][((blk ^ (qloc & 7)) << 3) + ((quad & 1) << 2)];
        uint2 pk;
        pk.x = pack_bf2(expfast(sacc[i][j][0]), expfast(sacc[i][j][1]));
        pk.y = pack_bf2(expfast(sacc[i][j][2]), expfast(sacc[i][j][3]));
        *(uint2*)pp = pk;
      }
    }
    // ---- O += P V' (x32; same-warp P rows, no barrier)
    #pragma unroll
    for (int kg = 0; kg < 2; kg++) {
      bf16x8 pf[2], vf[4];
      #pragma unroll
      for (int j = 0; j < 2; j++) {
        const int qloc = wq + j * 16 + c;
        const int blk = kg * 4 + quad;
        pf[j] = *(const bf16x8*)&Ps[qloc][(blk ^ (qloc & 7)) << 3];
      }
      #pragma unroll
      for (int dt = 0; dt < 4; dt++) {
        const int d = dt * 16 + c;
        const int vblk = kg * 4 + quad;
        vf[dt] = *(const bf16x8*)&Vs[buf][d * 64 + ((vblk ^ (d & 7)) << 3)];
      }
      #pragma unroll
      for (int j = 0; j < 2; j++)
        #pragma unroll
        for (int dt = 0; dt < 4; dt++)
          oacc[j][dt] = __builtin_amdgcn_mfma_f32_16x16x32_bf16(pf[j], vf[dt], oacc[j][dt], 0, 0, 0);
    }
  }
  #undef STAGE_KV
  // ---- epilogue: out1 = x + O
  #pragma unroll
  for (int j = 0; j < 2; j++)
    #pragma unroll
    for (int dt = 0; dt < 4; dt++)
      #pragma unroll
      for (int r = 0; r < 4; r++) {
        const int q = q0 + wq + j * 16 + quad * 4 + r;
        const int d = dt * 16 + c;
        size_t oi = ((size_t)(b * 4096 + q)) * 512 + h * 64 + d;
        out1[oi] = x[oi] + oacc[j][dt][r];
      }
}

// ---------------- launch ----------------
extern "C" void kernel_launch(void* const* d_in, const int* in_sizes, int n_in,
                              void* d_out, int out_size, void* d_ws, size_t ws_size,
                              hipStream_t stream) {
  const float* x  = (const float*)d_in[0];
  const float* g1 = (const float*)d_in[1];
  const float* b1 = (const float*)d_in[2];
  const float* W1 = (const float*)d_in[3];
  const float* g2 = (const float*)d_in[4];
  const float* b2 = (const float*)d_in[5];
  const float* Wa = (const float*)d_in[6];
  const float* ba = (const float*)d_in[7];
  const float* Wb = (const float*)d_in[8];
  const float* bb = (const float*)d_in[9];
  float* out = (float*)d_out;

  char* ws = (char*)d_ws;
  u16* w1b   = (u16*)(ws);                       // 1.5 MB
  u16* wab   = (u16*)(ws + 1572864);             // 1.5 MB
  u16* wbb   = (u16*)(ws + 3145728);             // 1.5 MB
  u16* h1    = (u16*)(ws + 4718592);             // 8 MB
  u16* qkv   = (u16*)(ws + 13107200);            // 24 MB
  u16* vt    = (u16*)(ws + 38273024);            // 8 MB
  u16* h2    = (u16*)(ws + 46661632);            // 8 MB
  u16* mid   = (u16*)(ws + 55050240);            // 24 MB (also rlpart before gemm1)
  float* o1  = (float*)(ws + 80478208);          // 16 MB
  float2* part  = (float2*)(ws + 97255424);      // 2 KB
  float* rlpart = (float*)(ws + 55050240);       // 512 KB, aliases mid (free until gemm1)

  cast_lnred<<<2560, 256, 0, stream>>>(W1, Wa, Wb, w1b, wab, wbb, x, part);
  ln_apply<<<4096, 256, 0, stream>>>(x, g1, b1, part, h1);

  gemm_bt<0><<<dim3(12, 64), 256, 0, stream>>>(h1, w1b, nullptr, nullptr, nullptr, qkv,
                                               8192, 1536, 512);
  attn_pass1<<<dim3(32, 16, 2), 256, 0, stream>>>(qkv, rlpart);
  vtrans<<<dim3(64, 16), 256, 0, stream>>>(qkv, rlpart, vt);
  attn_pass2<<<dim3(32, 16), 256, 0, stream>>>(qkv, vt, x, o1);

  ln_reduce<<<dim3(128, 2), 256, 0, stream>>>(o1, part);
  ln_apply<<<4096, 256, 0, stream>>>(o1, g2, b2, part, h2);

  gemm_bt<1><<<dim3(12, 64), 256, 0, stream>>>(h2, wab, ba, nullptr, nullptr, mid,
                                               8192, 1536, 512);
  gemm_bt<2><<<dim3(4, 64), 256, 0, stream>>>(mid, wbb, bb, o1, out, nullptr,
                                              8192, 512, 1536);
}

// Round 7
// 363.793 us; speedup vs baseline: 1.0855x; 1.0098x over previous
//
#include <hip/hip_runtime.h>
#include <math.h>

typedef __bf16 bf16x8 __attribute__((ext_vector_type(8)));
typedef __bf16 bf16x4 __attribute__((ext_vector_type(4)));
typedef short s16x4 __attribute__((ext_vector_type(4)));
typedef float f32x4 __attribute__((ext_vector_type(4)));
typedef unsigned int u32x2 __attribute__((ext_vector_type(2)));
typedef unsigned short u16;
typedef unsigned int u32;

// ---------------- helpers ----------------
__device__ __forceinline__ void gl_lds16(const void* g, void* l) {
  __builtin_amdgcn_global_load_lds(
      (const __attribute__((address_space(1))) void*)g,
      (__attribute__((address_space(3))) void*)l, 16, 0, 0);
}

__device__ __forceinline__ u16 f2bf(float x) {           // RNE f32->bf16
  union { float f; u32 u; } v; v.f = x;
  u32 r = v.u + 0x7FFFu + ((v.u >> 16) & 1u);
  return (u16)(r >> 16);
}

__device__ __forceinline__ float bflo(u32 u) {
  union { float f; u32 v; } t; t.v = u << 16; return t.f;
}
__device__ __forceinline__ float bfhi(u32 u) {
  union { float f; u32 v; } t; t.v = u & 0xFFFF0000u; return t.f;
}

// pack two positive floats to bf16x2 (round-half-up; cheap, bias < 2^-9 rel)
__device__ __forceinline__ u32 pack_bf2(float a, float b) {
  union { float f; u32 u; } ua, ub; ua.f = a; ub.f = b;
  return ((ua.u + 0x8000u) >> 16) | ((ub.u + 0x8000u) & 0xFFFF0000u);
}

// exp2 of pre-scaled input (Q carries 0.125*log2(e)) -> single v_exp_f32
__device__ __forceinline__ float expfast(float x) {
#if __has_builtin(__builtin_amdgcn_exp2f)
  return __builtin_amdgcn_exp2f(x);
#else
  return exp2f(x);
#endif
}

// x16 MFMA: same ~4.8cyc issue as x32 (half rate) — worth it only because the
// S^T C-tile == x16 A-frag identity keeps P in registers (no LDS round-trip).
__device__ __forceinline__ f32x4 mfma16(bf16x4 a, bf16x4 b, f32x4 c) {
#if __has_builtin(__builtin_amdgcn_mfma_f32_16x16x16_bf16)
  return __builtin_amdgcn_mfma_f32_16x16x16_bf16(a, b, c, 0, 0, 0);
#else
  return __builtin_amdgcn_mfma_f32_16x16x16bf16_1k(
      __builtin_bit_cast(s16x4, a), __builtin_bit_cast(s16x4, b), c, 0, 0, 0);
#endif
}

__device__ __forceinline__ float gelu_f(float v) {
  return 0.5f * v * (1.0f + erff(v * 0.7071067811865475f));
}

// ---------------- fused: cast 3 weight matrices + ln_reduce(x) ----------------
__global__ void cast_lnred(const float* __restrict__ s0, const float* __restrict__ s1,
                           const float* __restrict__ s2, u16* __restrict__ d0,
                           u16* __restrict__ d1, u16* __restrict__ d2,
                           const float* __restrict__ x, float2* __restrict__ part) {
  int blk = blockIdx.x;
  if (blk < 2304) {
    const float* s; u16* d;
    if (blk < 768)       { s = s0; d = d0; }
    else if (blk < 1536) { s = s1; d = d1; blk -= 768; }
    else                 { s = s2; d = d2; blk -= 1536; }
    int i = blk * 256 + threadIdx.x;
    float4 v = ((const float4*)s)[i];
    uint2 o;
    o.x = (u32)f2bf(v.x) | ((u32)f2bf(v.y) << 16);
    o.y = (u32)f2bf(v.z) | ((u32)f2bf(v.w) << 16);
    ((uint2*)d)[i] = o;
    return;
  }
  blk -= 2304;                       // 256 reduce blocks: [b(2)][i(128)]
  int b = blk >> 7, ib = blk & 127;
  const float4* p = (const float4*)(x + (size_t)b * 2097152 + (size_t)ib * 16384);
  float s = 0.f, q = 0.f;
  #pragma unroll
  for (int i = 0; i < 16; i++) {
    float4 v = p[i * 256 + threadIdx.x];
    s += v.x + v.y + v.z + v.w;
    q += v.x * v.x + v.y * v.y + v.z * v.z + v.w * v.w;
  }
  #pragma unroll
  for (int off = 32; off; off >>= 1) { s += __shfl_down(s, off, 64); q += __shfl_down(q, off, 64); }
  __shared__ float ls[4], lq[4];
  int w = threadIdx.x >> 6;
  if ((threadIdx.x & 63) == 0) { ls[w] = s; lq[w] = q; }
  __syncthreads();
  if (threadIdx.x == 0)
    part[b * 128 + ib] =
        make_float2(ls[0] + ls[1] + ls[2] + ls[3], lq[0] + lq[1] + lq[2] + lq[3]);
}

// ---------------- fused: o1 = x + oa + ob (split-k partials) + ln_reduce(o1) ----------------
__global__ void comb_lnred(const float* __restrict__ x, const u16* __restrict__ opart,
                           float* __restrict__ o1, float2* __restrict__ part) {
  int blk = blockIdx.x;              // 256 blocks x 16 iters x 256 thr x float4
  size_t base = (size_t)blk * 4096;
  const uint2* oa = (const uint2*)opart;
  const uint2* ob = (const uint2*)(opart + 4194304);
  float s = 0.f, q = 0.f;
  #pragma unroll
  for (int i = 0; i < 16; i++) {
    size_t idx = base + i * 256 + threadIdx.x;
    float4 v = ((const float4*)x)[idx];
    uint2 a = oa[idx];
    uint2 c = ob[idx];
    v.x += bflo(a.x) + bflo(c.x);
    v.y += bfhi(a.x) + bfhi(c.x);
    v.z += bflo(a.y) + bflo(c.y);
    v.w += bfhi(a.y) + bfhi(c.y);
    ((float4*)o1)[idx] = v;
    s += v.x + v.y + v.z + v.w;
    q += v.x * v.x + v.y * v.y + v.z * v.z + v.w * v.w;
  }
  #pragma unroll
  for (int off = 32; off; off >>= 1) { s += __shfl_down(s, off, 64); q += __shfl_down(q, off, 64); }
  __shared__ float ls[4], lq[4];
  int w = threadIdx.x >> 6;
  if ((threadIdx.x & 63) == 0) { ls[w] = s; lq[w] = q; }
  __syncthreads();
  if (threadIdx.x == 0)
    part[blk] = make_float2(ls[0] + ls[1] + ls[2] + ls[3], lq[0] + lq[1] + lq[2] + lq[3]);
}

// ---------------- ln_apply with inline final reduction (128 partials/batch) ----------------
__global__ void ln_apply(const float* __restrict__ src, const float* __restrict__ g,
                         const float* __restrict__ bta, const float2* __restrict__ part,
                         u16* __restrict__ dst) {
  int i = blockIdx.x * 256 + threadIdx.x;  // float4 index, 1048576 total
  int b = i >= 524288;
  int lane = threadIdx.x & 63;
  float2 a = part[b * 128 + lane], c2 = part[b * 128 + 64 + lane];
  float s = a.x + c2.x, q = a.y + c2.y;
  #pragma unroll
  for (int off = 32; off; off >>= 1) { s += __shfl_down(s, off, 64); q += __shfl_down(q, off, 64); }
  s = __shfl(s, 0, 64); q = __shfl(q, 0, 64);
  const float inv = 1.0f / 2097152.0f;
  float mu = s * inv;
  float rsig = rsqrtf(q * inv - mu * mu + 1e-5f);
  int r = i - b * 524288;
  float4 v = ((const float4*)src)[i];
  float4 gv = ((const float4*)g)[r];
  float4 bv = ((const float4*)bta)[r];
  float h0 = (v.x - mu) * rsig * gv.x + bv.x;
  float h1 = (v.y - mu) * rsig * gv.y + bv.y;
  float h2 = (v.z - mu) * rsig * gv.z + bv.z;
  float h3 = (v.w - mu) * rsig * gv.w + bv.w;
  uint2 o;
  o.x = (u32)f2bf(h0) | ((u32)f2bf(h1) << 16);
  o.y = (u32)f2bf(h2) | ((u32)f2bf(h3) << 16);
  ((uint2*)dst)[i] = o;
}

// ---------------- GEMM: out[m,n] = sum_k A[m,k]*B[n,k]  (B given row-major [N,K]) ----------------
// MODE 0: store bf16; cols<512 (Q) pre-scaled by 0.125*log2(e) so softmax exp is exp2.
// MODE 1: gelu(x+bias) -> bf16.  MODE 2: gelu(x+bias)+res -> fp32.
template <int MODE>
__global__ __launch_bounds__(256, 2)
void gemm_bt(const u16* __restrict__ A, const u16* __restrict__ Bm,
             const float* __restrict__ bias, const float* __restrict__ res,
             float* __restrict__ outf, u16* __restrict__ outb,
             int M, int N, int K) {
  __shared__ u16 As[128 * 32], Bs[128 * 32];
  const int tid = threadIdx.x;
  const int m0 = blockIdx.y * 128, n0 = blockIdx.x * 128;
  const int lane = tid & 63, w = tid >> 6;
  const int wm = (w >> 1) * 64, wn = (w & 1) * 64;
  const int c = lane & 15, quad = lane >> 4;
  const int arow = tid >> 2, acol = (tid & 3) * 8;

  const u16* gA = A + (size_t)(m0 + arow) * K + acol;
  const u16* gB = Bm + (size_t)(n0 + arow) * K + acol;
  u16* lA = As + tid * 8;
  u16* lB = Bs + tid * 8;

  f32x4 acc[4][4] = {};
  for (int kt = 0; kt < K; kt += 32) {
    gl_lds16(gA, lA);
    gl_lds16(gA + (size_t)64 * K, lA + 64 * 32);
    gl_lds16(gB, lB);
    gl_lds16(gB + (size_t)64 * K, lB + 64 * 32);
    gA += 32; gB += 32;
    __syncthreads();
    bf16x8 af[4], bf[4];
    #pragma unroll
    for (int i = 0; i < 4; i++) {
      af[i] = *(const bf16x8*)&As[(wm + i * 16 + c) * 32 + quad * 8];
      bf[i] = *(const bf16x8*)&Bs[(wn + i * 16 + c) * 32 + quad * 8];
    }
    #pragma unroll
    for (int i = 0; i < 4; i++)
      #pragma unroll
      for (int j = 0; j < 4; j++)
        acc[i][j] = __builtin_amdgcn_mfma_f32_16x16x32_bf16(af[i], bf[j], acc[i][j], 0, 0, 0);
    __syncthreads();
  }
  #pragma unroll
  for (int i = 0; i < 4; i++) {
    const int row0 = m0 + wm + i * 16 + quad * 4;
    #pragma unroll
    for (int j = 0; j < 4; j++) {
      const int col = n0 + wn + j * 16 + c;
      #pragma unroll
      for (int r = 0; r < 4; r++) {
        float v = acc[i][j][r];
        size_t oi = (size_t)(row0 + r) * N + col;
        if (MODE == 0 && col < 512) v *= 0.1803368801111204f;  // 1/8 * log2(e)
        if (MODE == 1 || MODE == 2) v = gelu_f(v + bias[col]);
        if (MODE == 2) outf[oi] = v + res[oi];
        else           outb[oi] = f2bf(v);
      }
    }
  }
}

// ---------------- attention pass 1: partial column sums of exp2(K Q^T) ----------------
__global__ __launch_bounds__(256, 4)
void attn_pass1(const u16* __restrict__ qkv, float* __restrict__ rlpart) {
  __shared__ u16 Qs[2][2 * 128 * 32];   // 2 buf x (2 panels x 128x32) = 32 KB
  const int tid = threadIdx.x;
  const int bh = blockIdx.y, b = bh >> 3, h = bh & 7;
  const int k0 = blockIdx.x * 128;
  const int lane = tid & 63, w = tid >> 6;
  const int wn = w * 32;                 // each warp owns 32 k-columns
  const int c = lane & 15, quad = lane >> 4;
  const int arow = tid >> 2, acol = (tid & 3) * 8;

  bf16x8 bk[2][2];
  {
    const u16* Kg = qkv + ((size_t)(b * 4096 + k0 + wn + c)) * 1536 + 512 + h * 64 + quad * 8;
    #pragma unroll
    for (int j = 0; j < 2; j++)
      #pragma unroll
      for (int ks = 0; ks < 2; ks++)
        bk[j][ks] = *(const bf16x8*)(Kg + (size_t)j * 16 * 1536 + ks * 32);
  }
  const u16* Qg = qkv + ((size_t)(b * 4096 + blockIdx.z * 2048)) * 1536 + h * 64;

  #define STAGE_Q(t)                                                              \
    {                                                                             \
      u16* dst = Qs[(t) & 1];                                                     \
      const u16* src = Qg + (size_t)((t) * 128) * 1536;                           \
      _Pragma("unroll")                                                           \
      for (int ks = 0; ks < 2; ks++)                                              \
        _Pragma("unroll")                                                         \
        for (int rr = 0; rr < 128; rr += 64)                                      \
          gl_lds16(src + (size_t)(rr + arow) * 1536 + ks * 32 + acol,             \
                   dst + ks * 4096 + (rr + arow) * 32 + acol);                    \
    }

  STAGE_Q(0);
  float s0 = 0.f, s1 = 0.f;
  for (int t = 0; t < 16; t++) {
    __syncthreads();
    if (t + 1 < 16) STAGE_Q(t + 1);
    const u16* buf = Qs[t & 1];
    #pragma unroll
    for (int i = 0; i < 8; i++) {
      bf16x8 a0 = *(const bf16x8*)&buf[(i * 16 + c) * 32 + quad * 8];
      bf16x8 a1 = *(const bf16x8*)&buf[4096 + (i * 16 + c) * 32 + quad * 8];
      f32x4 acc0 = {}, acc1 = {};
      acc0 = __builtin_amdgcn_mfma_f32_16x16x32_bf16(a0, bk[0][0], acc0, 0, 0, 0);
      acc0 = __builtin_amdgcn_mfma_f32_16x16x32_bf16(a1, bk[0][1], acc0, 0, 0, 0);
      acc1 = __builtin_amdgcn_mfma_f32_16x16x32_bf16(a0, bk[1][0], acc1, 0, 0, 0);
      acc1 = __builtin_amdgcn_mfma_f32_16x16x32_bf16(a1, bk[1][1], acc1, 0, 0, 0);
      #pragma unroll
      for (int r = 0; r < 4; r++) {
        s0 += expfast(acc0[r]);
        s1 += expfast(acc1[r]);
      }
    }
  }
  #undef STAGE_Q
  s0 += __shfl_xor(s0, 16, 64); s0 += __shfl_xor(s0, 32, 64);
  s1 += __shfl_xor(s1, 16, 64); s1 += __shfl_xor(s1, 32, 64);
  if (quad == 0) {
    float* rp = rlpart + ((size_t)blockIdx.z * 16 + bh) * 4096 + k0 + wn;
    rp[c] = s0;
    rp[16 + c] = s1;
  }
}

// ---------------- transpose+scale V (inline rl = 1/(part0+part1)) ----------------
// vt[bh][kt(64)][d(64)][(blk ^ (d&7)) * 8 + (k&7)] = V[k][d] * rl[bh][k]
__global__ void vtrans(const u16* __restrict__ qkv, const float* __restrict__ rlpart,
                       u16* __restrict__ vt) {
  __shared__ u16 t[64 * 66];
  __shared__ float rls[64];
  int bh = blockIdx.y, p0 = blockIdx.x * 64;
  int b = bh >> 3, h = bh & 7;
  const u16* src = qkv + ((size_t)(b * 4096 + p0)) * 1536 + 1024 + h * 64;
  int tid = threadIdx.x;
  if (tid < 64) {
    size_t idx = (size_t)bh * 4096 + p0 + tid;
    rls[tid] = 1.0f / (rlpart[idx] + rlpart[65536 + idx]);
  }
  __syncthreads();
  #pragma unroll
  for (int j = 0; j < 16; j++) {
    int idx = j * 256 + tid;
    int p = idx >> 6, d = idx & 63;
    union { float f; u32 u; } uv;
    uv.u = ((u32)src[(size_t)p * 1536 + d]) << 16;
    t[d * 66 + p] = f2bf(uv.f * rls[p]);
  }
  __syncthreads();
  u16* dst = vt + (size_t)bh * 262144 + (size_t)blockIdx.x * 4096;
  #pragma unroll
  for (int j = 0; j < 16; j++) {
    int idx = j * 256 + tid;
    int d = idx >> 6, p = idx & 63;
    dst[d * 64 + ((((p >> 3) & 7) ^ (d & 7)) << 3) + (p & 7)] = t[d * 66 + p];
  }
}

// ---------------- attention pass 2 (split-k): opart[z] = P@V' over k-half z ----------------
// R4's register-PV structure (no P LDS, 32 KB total) at 4 blocks/CU:
// grid (32 q-tiles, 16 bh, 2 k-halves) = 1024 = exactly 4 blocks/CU, no tail.
// S^T = K Q^T (x32, K rows as A); C-tile == x16 A-frag -> exp+pack in registers.
// K/V double-buffered, 1 barrier/t. O-half written as bf16 partial; residual +
// combine happen in comb_lnred.
__global__ __launch_bounds__(256, 4)
void attn_pass2(const u16* __restrict__ qkv, const u16* __restrict__ vt,
                u16* __restrict__ opart) {
  __shared__ u16 Ks[2][2][2048];  // [buf][dk-panel][64k x 32] = 16 KB
  __shared__ u16 Vs[2][4096];     // [buf][64d x 64k swizzled] = 16 KB
  const int tid = threadIdx.x;
  const int bh = blockIdx.y, b = bh >> 3, h = bh & 7;
  const int q0 = blockIdx.x * 128;
  const int kh = blockIdx.z;
  const int lane = tid & 63, w = tid >> 6;
  const int wq = w * 32;                 // each warp owns 32 q-rows
  const int c = lane & 15, quad = lane >> 4;

  // resident Q fragments (B-operand): q = q0+wq+j*16+c, dk = ks*32+quad*8
  bf16x8 bq[2][2];
  {
    const u16* Qg = qkv + ((size_t)(b * 4096 + q0 + wq + c)) * 1536 + h * 64 + quad * 8;
    #pragma unroll
    for (int j = 0; j < 2; j++)
      #pragma unroll
      for (int ks = 0; ks < 2; ks++)
        bq[j][ks] = *(const bf16x8*)(Qg + (size_t)j * 16 * 1536 + ks * 32);
  }
  const u16* Kg = qkv + ((size_t)(b * 4096 + kh * 2048)) * 1536 + 512 + h * 64;
  const u16* Vg = vt + (size_t)bh * 262144 + (size_t)kh * 131072;

  #define STAGE_KV(t)                                                             \
    {                                                                             \
      const int buf_ = (t) & 1;                                                   \
      const int krow_ = (t) * 64 + (tid >> 2);                                    \
      _Pragma("unroll")                                                           \
      for (int ks = 0; ks < 2; ks++)                                              \
        gl_lds16(Kg + (size_t)krow_ * 1536 + ks * 32 + (tid & 3) * 8,             \
                 &Ks[buf_][ks][tid * 8]);                                         \
      gl_lds16(Vg + (t) * 4096 + tid * 8, &Vs[buf_][tid * 8]);                    \
      gl_lds16(Vg + (t) * 4096 + 2048 + tid * 8, &Vs[buf_][2048 + tid * 8]);      \
    }

  STAGE_KV(0);
  f32x4 oacc[2][4] = {};
  for (int t = 0; t < 32; t++) {
    __syncthreads();                     // buf t ready (vmcnt drained at barrier)
    if (t + 1 < 32) STAGE_KV(t + 1);     // prefetch overlaps compute below
    const int buf = t & 1;

    // ---- S^T = K Q^T (4 k-tiles x 2 q-tiles)
    f32x4 sacc[4][2] = {};
    #pragma unroll
    for (int i = 0; i < 4; i++) {
      bf16x8 af0 = *(const bf16x8*)&Ks[buf][0][(i * 16 + c) * 32 + quad * 8];
      bf16x8 af1 = *(const bf16x8*)&Ks[buf][1][(i * 16 + c) * 32 + quad * 8];
      #pragma unroll
      for (int j = 0; j < 2; j++) {
        sacc[i][j] = __builtin_amdgcn_mfma_f32_16x16x32_bf16(af0, bq[j][0], sacc[i][j], 0, 0, 0);
        sacc[i][j] = __builtin_amdgcn_mfma_f32_16x16x32_bf16(af1, bq[j][1], sacc[i][j], 0, 0, 0);
      }
    }
    // ---- P = exp2(S^T), packed in-register into 16x16x16 A-fragments
    bf16x4 pa[4][2];
    #pragma unroll
    for (int i = 0; i < 4; i++)
      #pragma unroll
      for (int j = 0; j < 2; j++) {
        u32x2 pk;
        pk.x = pack_bf2(expfast(sacc[i][j][0]), expfast(sacc[i][j][1]));
        pk.y = pack_bf2(expfast(sacc[i][j][2]), expfast(sacc[i][j][3]));
        pa[i][j] = __builtin_bit_cast(bf16x4, pk);
      }
    // ---- O += P V' (x16; V B-frags b64 from swizzled Vs)
    #pragma unroll
    for (int kc = 0; kc < 4; kc++) {
      const int kb = 2 * kc + (quad >> 1);
      #pragma unroll
      for (int j2 = 0; j2 < 4; j2++) {
        const int d = j2 * 16 + c;
        bf16x4 vf = *(const bf16x4*)&Vs[buf][d * 64 + ((kb ^ (d & 7)) << 3) + 4 * (quad & 1)];
        oacc[0][j2] = mfma16(pa[kc][0], vf, oacc[0][j2]);
        oacc[1][j2] = mfma16(pa[kc][1], vf, oacc[1][j2]);
      }
    }
  }
  #undef STAGE_KV
  // ---- epilogue: bf16 partial (residual added in comb_lnred)
  u16* op = opart + (size_t)kh * 4194304;
  #pragma unroll
  for (int i2 = 0; i2 < 2; i2++)
    #pragma unroll
    for (int j2 = 0; j2 < 4; j2++)
      #pragma unroll
      for (int r = 0; r < 4; r++) {
        const int q = q0 + wq + i2 * 16 + quad * 4 + r;
        const int d = j2 * 16 + c;
        op[((size_t)(b * 4096 + q)) * 512 + h * 64 + d] = f2bf(oacc[i2][j2][r]);
      }
}

// ---------------- launch ----------------
extern "C" void kernel_launch(void* const* d_in, const int* in_sizes, int n_in,
                              void* d_out, int out_size, void* d_ws, size_t ws_size,
                              hipStream_t stream) {
  const float* x  = (const float*)d_in[0];
  const float* g1 = (const float*)d_in[1];
  const float* b1 = (const float*)d_in[2];
  const float* W1 = (const float*)d_in[3];
  const float* g2 = (const float*)d_in[4];
  const float* b2 = (const float*)d_in[5];
  const float* Wa = (const float*)d_in[6];
  const float* ba = (const float*)d_in[7];
  const float* Wb = (const float*)d_in[8];
  const float* bb = (const float*)d_in[9];
  float* out = (float*)d_out;

  char* ws = (char*)d_ws;
  u16* w1b   = (u16*)(ws);                       // 1.5 MB
  u16* wab   = (u16*)(ws + 1572864);             // 1.5 MB
  u16* wbb   = (u16*)(ws + 3145728);             // 1.5 MB
  u16* h1    = (u16*)(ws + 4718592);             // 8 MB
  u16* qkv   = (u16*)(ws + 13107200);            // 24 MB
  u16* vt    = (u16*)(ws + 38273024);            // 8 MB
  u16* h2    = (u16*)(ws + 46661632);            // 8 MB
  u16* mid   = (u16*)(ws + 55050240);            // 24 MB (also rlpart/opart earlier)
  float* o1  = (float*)(ws + 80478208);          // 16 MB
  float2* part  = (float2*)(ws + 97255424);      // 2 KB
  float* rlpart = (float*)(ws + 55050240);       // 512 KB, aliases mid (consumed by vtrans)
  u16* opart    = (u16*)(ws + 55050240);         // 16.8 MB, aliases mid (consumed by comb)

  cast_lnred<<<2560, 256, 0, stream>>>(W1, Wa, Wb, w1b, wab, wbb, x, part);
  ln_apply<<<4096, 256, 0, stream>>>(x, g1, b1, part, h1);

  gemm_bt<0><<<dim3(12, 64), 256, 0, stream>>>(h1, w1b, nullptr, nullptr, nullptr, qkv,
                                               8192, 1536, 512);
  attn_pass1<<<dim3(32, 16, 2), 256, 0, stream>>>(qkv, rlpart);
  vtrans<<<dim3(64, 16), 256, 0, stream>>>(qkv, rlpart, vt);
  attn_pass2<<<dim3(32, 16, 2), 256, 0, stream>>>(qkv, vt, opart);

  comb_lnred<<<256, 256, 0, stream>>>(x, opart, o1, part);
  ln_apply<<<4096, 256, 0, stream>>>(o1, g2, b2, part, h2);

  gemm_bt<1><<<dim3(12, 64), 256, 0, stream>>>(h2, wab, ba, nullptr, nullptr, mid,
                                               8192, 1536, 512);
  gemm_bt<2><<<dim3(4, 64), 256, 0, stream>>>(mid, wbb, bb, o1, out, nullptr,
                                              8192, 512, 1536);
}